// Round 3
// baseline (194.534 us; speedup 1.0000x reference)
//
#include <hip/hip_runtime.h>
#include <hip/hip_bf16.h>

// SparseDynamicConv3d: out[n,o] = sum_k sum_c feat[idx[k,n],c] * W[k,c,o]
// Round 3: LDS-free direct implicit GEMM. MFMA A/B fragments are loaded
// straight from global as 16B/lane b128s (A = bf16 feature gather, B = weights
// pre-transposed to [k][o][c64] with zero pad c in [48,64)). No barriers.

#define NVOX       100000
#define INC        48
#define INC_MAX    64
#define OUTC       64
#define OUTC_MAX   96
#define KOFF       27
#define FEAT_ELEMS (NVOX * INC)          // 4,800,000 bf16
#define WTB_ELEMS  (KOFF * OUTC * 64)    // 110,592 bf16 (c padded to 64)
#define FEAT_BLKS  2344                  // ceil(600000/256): 8 floats/thread
#define WTB_BLKS   432                   // 110592/256 exact
#define WS_NEED    ((size_t)(FEAT_ELEMS + 64 + WTB_ELEMS) * 2)

typedef __attribute__((ext_vector_type(8))) short  short8;
typedef __attribute__((ext_vector_type(4))) float  floatx4;

__device__ __forceinline__ short f2bf(float f) {
    union { __hip_bfloat16 h; short s; } u;
    u.h = __float2bfloat16(f);
    return u.s;
}

// featb: fp32 -> bf16 (+64-elem zero pad tail for safe chunk-6/7 overreads).
// wtb:   W[k, c<48, o] -> bf16 [k][o][c64], c in [48,64) = 0.0.
__global__ void __launch_bounds__(256)
prep_cvt(const float* __restrict__ feat, const float* __restrict__ wk,
         short* __restrict__ featb, short* __restrict__ wtb)
{
    int b = blockIdx.x;
    if (b < FEAT_BLKS) {
        int t = b * 256 + threadIdx.x;           // one thread = 8 floats
        if (t < FEAT_ELEMS / 8) {
            const floatx4* src = (const floatx4*)(feat + t * 8);
            floatx4 f0 = src[0], f1 = src[1];
            short8 p;
            #pragma unroll
            for (int j = 0; j < 4; ++j) { p[j] = f2bf(f0[j]); p[4 + j] = f2bf(f1[j]); }
            *(short8*)(featb + t * 8) = p;
        }
    } else {
        if (b == FEAT_BLKS && threadIdx.x < 64)  // zero the featb overread pad
            featb[FEAT_ELEMS + threadIdx.x] = 0;
        int t = (b - FEAT_BLKS) * 256 + threadIdx.x;   // 0..110591 exact
        int k = t >> 12, rem = t & 4095;
        int o = rem >> 6, c = rem & 63;
        wtb[t] = (c < INC) ? f2bf(wk[k * (INC_MAX * OUTC_MAX) + c * OUTC_MAX + o])
                           : (short)0;
    }
}

template<bool PRE>
__global__ void __launch_bounds__(256, 4)
spconv_direct(const void* __restrict__ featp, const void* __restrict__ wp,
              const int* __restrict__ idx, float* __restrict__ out)
{
    const int lane = threadIdx.x & 63;
    const int wave = threadIdx.x >> 6;
    const int quad = lane >> 4;
    const int l16  = lane & 15;
    const int m0   = (blockIdx.x * 4 + wave) * 32;   // this wave's 32-row base
    const int r0   = m0 + l16;                       // row for mt=0 frag
    const int r1   = m0 + 16 + l16;                  // row for mt=1 frag
    const bool v0  = r0 < NVOX, v1 = r1 < NVOX;

    floatx4 acc[2][4];
    #pragma unroll
    for (int i = 0; i < 2; ++i)
        #pragma unroll
        for (int j = 0; j < 4; ++j)
            acc[i][j] = (floatx4){0.f, 0.f, 0.f, 0.f};

    short8 a[2][2][2];   // [buf][mt][ks]
    const short8 z8 = (short8){0, 0, 0, 0, 0, 0, 0, 0};

    // A fragment load: lane (quad,l16) reads 16B chunks (ks*4+quad) of rows g0/g1.
    auto aload = [&](short8 (*dst)[2], int g0, int g1) {
        if (PRE) {
            const short* fb = (const short*)featp;
            const short8* p0 = (const short8*)(fb + (g0 < 0 ? 0 : g0) * INC + quad * 8);
            const short8* p1 = (const short8*)(fb + (g1 < 0 ? 0 : g1) * INC + quad * 8);
            short8 t00 = p0[0], t01 = p0[4];   // ks=0 / ks=1 (+64B)
            short8 t10 = p1[0], t11 = p1[4];
            dst[0][0] = (g0 < 0) ? z8 : t00;  dst[0][1] = (g0 < 0) ? z8 : t01;
            dst[1][0] = (g1 < 0) ? z8 : t10;  dst[1][1] = (g1 < 0) ? z8 : t11;
        } else {
            const float* ff = (const float*)featp;
            #pragma unroll
            for (int mt = 0; mt < 2; ++mt) {
                int g = mt ? g1 : g0;
                const float* row = ff + (g < 0 ? 0 : g) * INC + quad * 8;
                short8 s0, s1;
                #pragma unroll
                for (int j = 0; j < 8; ++j) s0[j] = f2bf(row[j]);
                if (quad < 2) {    // ks=1 chunks 4,5 valid; 6,7 would read OOB fp32
                    #pragma unroll
                    for (int j = 0; j < 8; ++j) s1[j] = f2bf(row[32 + j]);
                } else s1 = z8;
                dst[mt][0] = (g < 0) ? z8 : s0;
                dst[mt][1] = (g < 0) ? z8 : s1;
            }
        }
    };

    // prologue: idx two ahead, A one ahead
    int g0c = v0 ? idx[r0] : -1;
    int g1c = v1 ? idx[r1] : -1;
    int g0n = v0 ? idx[NVOX + r0] : -1;
    int g1n = v1 ? idx[NVOX + r1] : -1;
    aload(a[0], g0c, g1c);

    #pragma unroll
    for (int k = 0; k < KOFF; ++k) {
        // idx for k+2
        int g0f = -1, g1f = -1;
        if (k + 2 < KOFF) {
            g0f = v0 ? idx[(k + 2) * NVOX + r0] : -1;
            g1f = v1 ? idx[(k + 2) * NVOX + r1] : -1;
        }
        // A for k+1
        if (k + 1 < KOFF) aload(a[(k + 1) & 1], g0n, g1n);

        // B for k: 8 frags, one vaddr + imm offsets on the PRE path
        short8 b[2][4];
        if (PRE) {
            const short8* wb = (const short8*)((const short*)wp +
                               k * (OUTC * 64) + l16 * 64 + quad * 8);
            #pragma unroll
            for (int ks = 0; ks < 2; ++ks)
                #pragma unroll
                for (int nt = 0; nt < 4; ++nt)
                    b[ks][nt] = wb[nt * 128 + ks * 4];
        } else {
            const float* w = (const float*)wp + k * (INC_MAX * OUTC_MAX);
            #pragma unroll
            for (int ks = 0; ks < 2; ++ks)
                #pragma unroll
                for (int nt = 0; nt < 4; ++nt) {
                    short8 f;
                    #pragma unroll
                    for (int j = 0; j < 8; ++j) {
                        int c = ks * 32 + quad * 8 + j;
                        f[j] = (c < INC) ? f2bf(w[c * OUTC_MAX + nt * 16 + l16])
                                         : (short)0;
                    }
                    b[ks][nt] = f;
                }
        }

        #pragma unroll
        for (int ks = 0; ks < 2; ++ks)
            #pragma unroll
            for (int mt = 0; mt < 2; ++mt)
                #pragma unroll
                for (int nt = 0; nt < 4; ++nt)
                    acc[mt][nt] = __builtin_amdgcn_mfma_f32_16x16x32_bf16(
                        a[k & 1][mt][ks], b[ks][nt], acc[mt][nt], 0, 0, 0);

        g0n = g0f; g1n = g1f;
    }

    // epilogue: D[row=quad*4+r][col=l16]
    #pragma unroll
    for (int mt = 0; mt < 2; ++mt) {
        int gbase = m0 + mt * 16 + quad * 4;
        #pragma unroll
        for (int r = 0; r < 4; ++r) {
            if (gbase + r < NVOX) {
                #pragma unroll
                for (int nt = 0; nt < 4; ++nt)
                    out[(gbase + r) * OUTC + nt * 16 + l16] = acc[mt][nt][r];
            }
        }
    }
}

extern "C" void kernel_launch(void* const* d_in, const int* in_sizes, int n_in,
                              void* d_out, int out_size, void* d_ws, size_t ws_size,
                              hipStream_t stream) {
    const float* feat = (const float*)d_in[0];
    const float* wk   = (const float*)d_in[1];
    const int*   idx  = (const int*)d_in[2];
    float* out = (float*)d_out;

    const int nwaves = NVOX / 32;                    // 3125
    const int grid   = (nwaves + 3) / 4;             // 782 blocks x 4 waves

    if (ws_size >= WS_NEED) {
        short* featb = (short*)d_ws;
        short* wtb   = featb + FEAT_ELEMS + 64;      // 16B-aligned offset
        prep_cvt<<<FEAT_BLKS + WTB_BLKS, 256, 0, stream>>>(feat, wk, featb, wtb);
        spconv_direct<true><<<grid, 256, 0, stream>>>(featb, wtb, idx, out);
    } else {
        spconv_direct<false><<<grid, 256, 0, stream>>>(feat, wk, idx, out);
    }
}

// Round 4
// 115.356 us; speedup vs baseline: 1.6864x; 1.6864x over previous
//
#include <hip/hip_runtime.h>
#include <hip/hip_bf16.h>

// SparseDynamicConv3d: out[n,o] = sum_k sum_c feat[idx[k,n],c] * W[k,c,o]
// Round 4: A = direct per-lane register gather from 128B-aligned bf16 rows
// (prefetched 1 iter ahead); B = frag-packed LDS double-buffer, linear
// conflict-free lane*16 addressing, 1 barrier/iter; launch_bounds(256,3) so
// the pipeline registers fit; XCD-contiguous block swizzle for L2 locality.

#define NVOX       100000
#define INC        48
#define INC_MAX    64
#define OUTC       64
#define OUTC_MAX   96
#define KOFF       27
#define FEAT_ROW   64                       // bf16 row padded to 128 B, c>=48 zero
#define FEATB_ELEMS (NVOX * FEAT_ROW)       // 6.4M shorts = 12.8 MB
#define WTB_ELEMS  (KOFF * 4096)            // frag-packed: [k][frag8][lane64][8]
#define WS_NEED    ((size_t)(FEATB_ELEMS + WTB_ELEMS) * 2)
#define FEAT_PREP_BLKS 3125                 // 800000 threads / 256, exact
#define WTB_PREP_BLKS  432                  // 110592 / 256, exact
#define MAIN_BLOCKS 782                     // ceil(100000/32 waves / 4)

typedef __attribute__((ext_vector_type(8))) short  short8;
typedef __attribute__((ext_vector_type(4))) float  floatx4;

__device__ __forceinline__ short f2bf(float f) {
    union { __hip_bfloat16 h; short s; } u;
    u.h = __float2bfloat16(f);
    return u.s;
}

// featb: [n][64] bf16, c in [48,64) zeroed (rows 128B-aligned -> 1 L2 line).
// wtb:   frag-packed [k][frag][lane][8]: frag=ks*4+nt, lane=quad*16+l16 holds
//        B[o=nt*16+l16][c=ks*32+quad*8+j] (c>=48 -> 0).
__global__ void __launch_bounds__(256)
prep_cvt(const float* __restrict__ feat, const float* __restrict__ wk,
         short* __restrict__ featb, short* __restrict__ wtb)
{
    int b = blockIdx.x;
    if (b < FEAT_PREP_BLKS) {
        int t = b * 256 + threadIdx.x;       // < 800000
        int g = t >> 3, c8 = (t & 7) * 8;
        short8 p = (short8){0, 0, 0, 0, 0, 0, 0, 0};
        if (c8 < INC) {
            const floatx4* src = (const floatx4*)(feat + g * INC + c8);
            floatx4 f0 = src[0], f1 = src[1];
            #pragma unroll
            for (int j = 0; j < 4; ++j) { p[j] = f2bf(f0[j]); p[4 + j] = f2bf(f1[j]); }
        }
        *(short8*)(featb + g * FEAT_ROW + c8) = p;
    } else {
        int t = (b - FEAT_PREP_BLKS) * 256 + threadIdx.x;   // < 110592 exact
        int k = t >> 12, r = t & 4095;
        int frag = r >> 9, lane = (r >> 3) & 63, j = t & 7;
        int ks = frag >> 2, nt = frag & 3, quad = lane >> 4, l16 = lane & 15;
        int o = nt * 16 + l16, c = ks * 32 + quad * 8 + j;
        wtb[t] = (c < INC) ? f2bf(wk[k * (INC_MAX * OUTC_MAX) + c * OUTC_MAX + o])
                           : (short)0;
    }
}

__global__ void __launch_bounds__(256, 3)
spconv_main(const short* __restrict__ featb, const short* __restrict__ wtb,
            const int* __restrict__ idx, float* __restrict__ out)
{
    __shared__ short Bs[2][4096];            // 2 x 8 KB B frag buffers

    const int tid  = threadIdx.x;
    const int lane = tid & 63;
    const int wave = tid >> 6;
    const int quad = lane >> 4;
    const int l16  = lane & 15;

    // XCD-contiguous swizzle: bid -> (bid&7)*97 + bid>>3 for bid<776 (bijective),
    // tail 776..781 identity. Each XCD's L2 then covers ~1/8 of featb + halo.
    int bid = blockIdx.x;
    int sb  = (bid < 776) ? ((bid & 7) * 97 + (bid >> 3)) : bid;

    const int m0 = (sb * 4 + wave) * 32;
    const int r0 = m0 + l16;
    const int r1 = m0 + 16 + l16;
    const bool v0 = r0 < NVOX, v1 = r1 < NVOX;

    const short8 z8 = (short8){0, 0, 0, 0, 0, 0, 0, 0};

    floatx4 acc[2][4];
    #pragma unroll
    for (int i = 0; i < 2; ++i)
        #pragma unroll
        for (int j = 0; j < 4; ++j)
            acc[i][j] = (floatx4){0.f, 0.f, 0.f, 0.f};

    short8 a[2][2][2];   // [buf][mt][ks]

    // A-frag gather: lane (quad,l16) reads 16B chunk quad (ks0) / quad+4 (ks1)
    // of rows g0 (mt=0) and g1 (mt=1). Rows are 128B, c>=48 already zero.
    auto aload = [&](short8 dst[2][2], int g0, int g1) {
        const short8* p0 = (const short8*)(featb + (g0 < 0 ? 0 : g0) * FEAT_ROW);
        const short8* p1 = (const short8*)(featb + (g1 < 0 ? 0 : g1) * FEAT_ROW);
        short8 t00 = p0[quad], t01 = p0[quad + 4];
        short8 t10 = p1[quad], t11 = p1[quad + 4];
        dst[0][0] = (g0 < 0) ? z8 : t00;  dst[0][1] = (g0 < 0) ? z8 : t01;
        dst[1][0] = (g1 < 0) ? z8 : t10;  dst[1][1] = (g1 < 0) ? z8 : t11;
    };

    // ---- prologue: idx(0), idx(1); A(0); B-stage regs for k=0 ----
    int g0c = v0 ? idx[r0] : -1;
    int g1c = v1 ? idx[r1] : -1;
    int g0n = v0 ? idx[NVOX + r0] : -1;
    int g1n = v1 ? idx[NVOX + r1] : -1;
    aload(a[0], g0c, g1c);
    short8 bst0 = *(const short8*)(wtb + tid * 8);
    short8 bst1 = *(const short8*)(wtb + tid * 8 + 2048);

    #pragma unroll
    for (int k = 0; k < KOFF; ++k) {
        // commit staged B(k) regs (loaded last iter) to LDS buf[k&1]
        *(short8*)&Bs[k & 1][tid * 8]        = bst0;
        *(short8*)&Bs[k & 1][tid * 8 + 2048] = bst1;
        __syncthreads();

        // issue next-iteration global loads (a full iteration of cover time)
        if (k + 1 < KOFF) {
            bst0 = *(const short8*)(wtb + (k + 1) * 4096 + tid * 8);
            bst1 = *(const short8*)(wtb + (k + 1) * 4096 + tid * 8 + 2048);
            aload(a[(k + 1) & 1], g0n, g1n);
        }
        int g0f = -1, g1f = -1;
        if (k + 2 < KOFF) {
            g0f = v0 ? idx[(k + 2) * NVOX + r0] : -1;
            g1f = v1 ? idx[(k + 2) * NVOX + r1] : -1;
        }

        // B frags: linear lane*16 reads, conflict-free
        short8 b[2][4];
        #pragma unroll
        for (int ks = 0; ks < 2; ++ks)
            #pragma unroll
            for (int nt = 0; nt < 4; ++nt)
                b[ks][nt] = *(const short8*)&Bs[k & 1][(ks * 4 + nt) * 512 + lane * 8];

        #pragma unroll
        for (int ks = 0; ks < 2; ++ks)
            #pragma unroll
            for (int mt = 0; mt < 2; ++mt)
                #pragma unroll
                for (int nt = 0; nt < 4; ++nt)
                    acc[mt][nt] = __builtin_amdgcn_mfma_f32_16x16x32_bf16(
                        a[k & 1][mt][ks], b[ks][nt], acc[mt][nt], 0, 0, 0);

        g0n = g0f; g1n = g1f;
    }

    // epilogue: D[row=quad*4+r][col=l16]
    #pragma unroll
    for (int mt = 0; mt < 2; ++mt) {
        int gbase = m0 + mt * 16 + quad * 4;
        #pragma unroll
        for (int r = 0; r < 4; ++r) {
            if (gbase + r < NVOX) {
                #pragma unroll
                for (int nt = 0; nt < 4; ++nt)
                    out[(gbase + r) * OUTC + nt * 16 + l16] = acc[mt][nt][r];
            }
        }
    }
}

// Safety fallback (never taken with the observed 256 MB workspace): plain fp32.
__global__ void __launch_bounds__(256)
spconv_fallback(const float* __restrict__ feat, const float* __restrict__ wk,
                const int* __restrict__ idx, float* __restrict__ out)
{
    int t = blockIdx.x * 256 + threadIdx.x;
    if (t >= NVOX * OUTC) return;
    int n = t >> 6, o = t & 63;
    float s = 0.f;
    for (int k = 0; k < KOFF; ++k) {
        int g = idx[k * NVOX + n];
        if (g >= 0) {
            const float* fr = feat + g * INC;
            const float* wr = wk + k * (INC_MAX * OUTC_MAX) + o;
            #pragma unroll 8
            for (int c = 0; c < INC; ++c) s += fr[c] * wr[c * OUTC_MAX];
        }
    }
    out[t] = s;
}

extern "C" void kernel_launch(void* const* d_in, const int* in_sizes, int n_in,
                              void* d_out, int out_size, void* d_ws, size_t ws_size,
                              hipStream_t stream) {
    const float* feat = (const float*)d_in[0];
    const float* wk   = (const float*)d_in[1];
    const int*   idx  = (const int*)d_in[2];
    float* out = (float*)d_out;

    if (ws_size >= WS_NEED) {
        short* featb = (short*)d_ws;
        short* wtb   = featb + FEATB_ELEMS;   // 12.8 MB offset, 16B-aligned
        prep_cvt<<<FEAT_PREP_BLKS + WTB_PREP_BLKS, 256, 0, stream>>>(feat, wk, featb, wtb);
        spconv_main<<<MAIN_BLOCKS, 256, 0, stream>>>(featb, wtb, idx, out);
    } else {
        spconv_fallback<<<(NVOX * OUTC + 255) / 256, 256, 0, stream>>>(feat, wk, idx, out);
    }
}

// Round 5
// 115.004 us; speedup vs baseline: 1.6915x; 1.0031x over previous
//
#include <hip/hip_runtime.h>
#include <hip/hip_bf16.h>

// SparseDynamicConv3d: out[n,o] = sum_k sum_c feat[idx[k,n],c] * W[k,c,o]
// Round 5: phase-paired K-loop (2 offsets per barrier, 14 barriers), 4 LDS
// B-buffers (32KB), A gathered direct-to-register 2 phases deep, idx 2 phases
// deep, dedicated zero-row for idx<0 (no per-frag cndmask). Layouts identical
// to r4 (verified correct, 0 bank conflicts).

#define NVOX       100000
#define INC        48
#define INC_MAX    64
#define OUTC       64
#define OUTC_MAX   96
#define KOFF       27
#define FEAT_ROW   64                        // bf16 row padded to 128 B
#define FEATB_ELEMS ((NVOX + 1) * FEAT_ROW)  // +1 zero row for idx<0
#define WTB_ELEMS  (KOFF * 4096)             // frag-packed [k][frag][lane][8]
#define WS_NEED    ((size_t)(FEATB_ELEMS + WTB_ELEMS) * 2)
#define FEAT_THREADS ((NVOX + 1) * 8)        // 800008
#define FEAT_PREP_BLKS ((FEAT_THREADS + 255) / 256)   // 3126
#define WTB_PREP_BLKS  432                   // 110592 / 256 exact
#define MAIN_BLOCKS 782

typedef __attribute__((ext_vector_type(8))) short  short8;
typedef __attribute__((ext_vector_type(4))) float  floatx4;

__device__ __forceinline__ short f2bf(float f) {
    union { __hip_bfloat16 h; short s; } u;
    u.h = __float2bfloat16(f);
    return u.s;
}

// featb: [n][64] bf16, c in [48,64) zero, row NVOX all-zero (idx<0 target).
// wtb:   frag-packed [k][frag][lane][8]: frag=ks*4+nt, lane=quad*16+l16 holds
//        B[o=nt*16+l16][c=ks*32+quad*8+j] (c>=48 -> 0).
__global__ void __launch_bounds__(256)
prep_cvt(const float* __restrict__ feat, const float* __restrict__ wk,
         short* __restrict__ featb, short* __restrict__ wtb)
{
    int b = blockIdx.x;
    if (b < FEAT_PREP_BLKS) {
        int t = b * 256 + threadIdx.x;
        if (t < FEAT_THREADS) {
            int g = t >> 3, c8 = (t & 7) * 8;
            short8 p = (short8){0, 0, 0, 0, 0, 0, 0, 0};
            if (g < NVOX && c8 < INC) {
                const floatx4* src = (const floatx4*)(feat + g * INC + c8);
                floatx4 f0 = src[0], f1 = src[1];
                #pragma unroll
                for (int j = 0; j < 4; ++j) { p[j] = f2bf(f0[j]); p[4 + j] = f2bf(f1[j]); }
            }
            *(short8*)(featb + g * FEAT_ROW + c8) = p;
        }
    } else {
        int t = (b - FEAT_PREP_BLKS) * 256 + threadIdx.x;   // < 110592 exact
        int k = t >> 12, r = t & 4095;
        int frag = r >> 9, lane = (r >> 3) & 63, j = t & 7;
        int ks = frag >> 2, nt = frag & 3, quad = lane >> 4, l16 = lane & 15;
        int o = nt * 16 + l16, c = ks * 32 + quad * 8 + j;
        wtb[t] = (c < INC) ? f2bf(wk[k * (INC_MAX * OUTC_MAX) + c * OUTC_MAX + o])
                           : (short)0;
    }
}

__global__ void __launch_bounds__(256, 3)
spconv_main(const short* __restrict__ featb, const short* __restrict__ wtb,
            const int* __restrict__ idx, float* __restrict__ out)
{
    __shared__ short Bs[2][2][4096];   // [pair-buffer][sub-k][8KB frag tile]

    const int tid  = threadIdx.x;
    const int lane = tid & 63;
    const int wave = tid >> 6;
    const int quad = lane >> 4;
    const int l16  = lane & 15;

    // XCD-contiguous swizzle (bijective for bid<776, identity tail)
    int bid = blockIdx.x;
    int sb  = (bid < 776) ? ((bid & 7) * 97 + (bid >> 3)) : bid;

    const int m0 = (sb * 4 + wave) * 32;
    const int r0 = m0 + l16;
    const int r1 = m0 + 16 + l16;
    const bool v0 = r0 < NVOX, v1 = r1 < NVOX;
    const int rr0 = v0 ? r0 : 0;     // safe idx addr for OOB tail waves
    const int rr1 = v1 ? r1 : 0;

    floatx4 acc[2][4];
    #pragma unroll
    for (int i = 0; i < 2; ++i)
        #pragma unroll
        for (int j = 0; j < 4; ++j)
            acc[i][j] = (floatx4){0.f, 0.f, 0.f, 0.f};

    short8 A[4][2][2];    // [k&3][mt][ks] A-frag ring, 2 phases deep
    short8 bst[4][2];     // [k&3][half]  B-stage ring
    int    row0[4], row1[4];   // gathered row indices (idx<0 -> NVOX zero row)

    auto ldrow = [&](int k) {
        int t0 = idx[k * NVOX + rr0];
        int t1 = idx[k * NVOX + rr1];
        row0[k & 3] = (t0 < 0) ? NVOX : t0;
        row1[k & 3] = (t1 < 0) ? NVOX : t1;
    };
    auto aload = [&](int k) {
        const short8* p0 = (const short8*)(featb + row0[k & 3] * FEAT_ROW);
        const short8* p1 = (const short8*)(featb + row1[k & 3] * FEAT_ROW);
        A[k & 3][0][0] = p0[quad];  A[k & 3][0][1] = p0[quad + 4];
        A[k & 3][1][0] = p1[quad];  A[k & 3][1][1] = p1[quad + 4];
    };
    auto bload = [&](int k) {
        bst[k & 3][0] = *(const short8*)(wtb + k * 4096 + tid * 8);
        bst[k & 3][1] = *(const short8*)(wtb + k * 4096 + tid * 8 + 2048);
    };
    auto compute = [&](int k, int pb, int sub) {
        #pragma unroll
        for (int ks = 0; ks < 2; ++ks) {
            short8 b[4];
            #pragma unroll
            for (int nt = 0; nt < 4; ++nt)
                b[nt] = *(const short8*)&Bs[pb][sub][(ks * 4 + nt) * 512 + lane * 8];
            #pragma unroll
            for (int mt = 0; mt < 2; ++mt)
                #pragma unroll
                for (int nt = 0; nt < 4; ++nt)
                    acc[mt][nt] = __builtin_amdgcn_mfma_f32_16x16x32_bf16(
                        A[k & 3][mt][ks], b[nt], acc[mt][nt], 0, 0, 0);
        }
    };

    // ---- prologue: idx(0..3), A(0..1), B-stage(0..1) ----
    ldrow(0); ldrow(1); ldrow(2); ldrow(3);
    aload(0); aload(1);
    bload(0); bload(1);

    #pragma unroll
    for (int j = 0; j < 14; ++j) {
        const int kk = 2 * j;
        const int pb = j & 1;

        // commit staged B(kk), B(kk+1) to LDS
        *(short8*)&Bs[pb][0][tid * 8]        = bst[kk & 3][0];
        *(short8*)&Bs[pb][0][tid * 8 + 2048] = bst[kk & 3][1];
        if (kk + 1 < KOFF) {
            *(short8*)&Bs[pb][1][tid * 8]        = bst[(kk + 1) & 3][0];
            *(short8*)&Bs[pb][1][tid * 8 + 2048] = bst[(kk + 1) & 3][1];
        }
        __syncthreads();

        // prefetch: A/B for kk+2,kk+3 (2-phase cover), idx for kk+4,kk+5
        if (kk + 2 < KOFF) { aload(kk + 2); bload(kk + 2); }
        if (kk + 3 < KOFF) { aload(kk + 3); bload(kk + 3); }
        if (kk + 4 < KOFF) ldrow(kk + 4);
        if (kk + 5 < KOFF) ldrow(kk + 5);

        compute(kk, pb, 0);
        if (kk + 1 < KOFF) compute(kk + 1, pb, 1);
    }

    // ---- epilogue: D[row=quad*4+r][col=l16] ----
    #pragma unroll
    for (int mt = 0; mt < 2; ++mt) {
        int gbase = m0 + mt * 16 + quad * 4;
        #pragma unroll
        for (int r = 0; r < 4; ++r) {
            if (gbase + r < NVOX) {
                #pragma unroll
                for (int nt = 0; nt < 4; ++nt)
                    out[(gbase + r) * OUTC + nt * 16 + l16] = acc[mt][nt][r];
            }
        }
    }
}

// Safety fallback (only if workspace were too small): plain fp32.
__global__ void __launch_bounds__(256)
spconv_fallback(const float* __restrict__ feat, const float* __restrict__ wk,
                const int* __restrict__ idx, float* __restrict__ out)
{
    int t = blockIdx.x * 256 + threadIdx.x;
    if (t >= NVOX * OUTC) return;
    int n = t >> 6, o = t & 63;
    float s = 0.f;
    for (int k = 0; k < KOFF; ++k) {
        int g = idx[k * NVOX + n];
        if (g >= 0) {
            const float* fr = feat + g * INC;
            const float* wr = wk + k * (INC_MAX * OUTC_MAX) + o;
            #pragma unroll 8
            for (int c = 0; c < INC; ++c) s += fr[c] * wr[c * OUTC_MAX];
        }
    }
    out[t] = s;
}

extern "C" void kernel_launch(void* const* d_in, const int* in_sizes, int n_in,
                              void* d_out, int out_size, void* d_ws, size_t ws_size,
                              hipStream_t stream) {
    const float* feat = (const float*)d_in[0];
    const float* wk   = (const float*)d_in[1];
    const int*   idx  = (const int*)d_in[2];
    float* out = (float*)d_out;

    if (ws_size >= WS_NEED) {
        short* featb = (short*)d_ws;
        short* wtb   = featb + FEATB_ELEMS;
        prep_cvt<<<FEAT_PREP_BLKS + WTB_PREP_BLKS, 256, 0, stream>>>(feat, wk, featb, wtb);
        spconv_main<<<MAIN_BLOCKS, 256, 0, stream>>>(featb, wtb, idx, out);
    } else {
        spconv_fallback<<<(NVOX * OUTC + 255) / 256, 256, 0, stream>>>(feat, wk, idx, out);
    }
}

// Round 6
// 108.361 us; speedup vs baseline: 1.7952x; 1.0613x over previous
//
#include <hip/hip_runtime.h>
#include <hip/hip_bf16.h>

// SparseDynamicConv3d: out[n,o] = sum_k sum_c feat[idx[k,n],c] * W[k,c,o]
// Round 6: switch to mfma_f32_32x32x16_bf16 with K=48 EXACT (3 k-steps, no
// 48->64 zero padding): -38% MFMA issue cycles, -25% B LDS bytes, 3 instead
// of 4 A-gather b128s per wave/k, one idx load per lane/k. Pipeline skeleton
// from r4 (1 barrier per k-pair, 4x6KB LDS buffers, shallow reg rings).

#define NVOX       100000
#define INC        48
#define INC_MAX    64
#define OUTC       64
#define OUTC_MAX   96
#define KOFF       27
#define FEAT_ROW   64                        // bf16 row padded to 128 B
#define FEATB_ELEMS ((NVOX + 1) * FEAT_ROW)  // +1 zero row for idx<0
#define WTB_K      3072                      // shorts per k: 48x64, frag-packed
#define WTB_ELEMS  (KOFF * WTB_K)            // 82944
#define WS_NEED    ((size_t)(FEATB_ELEMS + WTB_ELEMS) * 2)
#define FEAT_THREADS ((NVOX + 1) * 8)        // 800008
#define FEAT_PREP_BLKS ((FEAT_THREADS + 255) / 256)   // 3126
#define WTB_PREP_BLKS  (WTB_ELEMS / 256)     // 324 exact
#define MAIN_BLOCKS 782                      // 3125 waves of 32 rows, +3 idle

typedef __attribute__((ext_vector_type(8)))  short short8;
typedef __attribute__((ext_vector_type(4)))  float floatx4;
typedef __attribute__((ext_vector_type(16))) float floatx16;

__device__ __forceinline__ short f2bf(float f) {
    union { __hip_bfloat16 h; short s; } u;
    u.h = __float2bfloat16(f);
    return u.s;
}

// featb: [n][64] bf16, c in [48,64) zero, row NVOX all-zero (idx<0 target).
// wtb:   frag-packed per k as 384 16B chunks: chunk = (ks*2+nt)*64 + lane,
//        element j: B[c = ks*16 + (lane>>5)*8 + j][o = nt*32 + (lane&31)],
//        matching the 32x32x16 B-operand layout (k=(lane>>5)*8+j, n=lane&31).
__global__ void __launch_bounds__(256)
prep_cvt(const float* __restrict__ feat, const float* __restrict__ wk,
         short* __restrict__ featb, short* __restrict__ wtb)
{
    int b = blockIdx.x;
    if (b < FEAT_PREP_BLKS) {
        int t = b * 256 + threadIdx.x;
        if (t < FEAT_THREADS) {
            int g = t >> 3, c8 = (t & 7) * 8;
            short8 p = (short8){0, 0, 0, 0, 0, 0, 0, 0};
            if (g < NVOX && c8 < INC) {
                const floatx4* src = (const floatx4*)(feat + g * INC + c8);
                floatx4 f0 = src[0], f1 = src[1];
                #pragma unroll
                for (int j = 0; j < 4; ++j) { p[j] = f2bf(f0[j]); p[4 + j] = f2bf(f1[j]); }
            }
            *(short8*)(featb + g * FEAT_ROW + c8) = p;
        }
    } else {
        int t = (b - FEAT_PREP_BLKS) * 256 + threadIdx.x;   // < 82944 exact
        int k = t / WTB_K, r = t % WTB_K;
        int chunk = r >> 3, j = r & 7;
        int f = chunk >> 6, lane = chunk & 63;
        int ks = f >> 1, nt = f & 1;
        int c = ks * 16 + (lane >> 5) * 8 + j;      // 0..47, no pad
        int o = nt * 32 + (lane & 31);
        wtb[t] = f2bf(wk[k * (INC_MAX * OUTC_MAX) + c * OUTC_MAX + o]);
    }
}

__global__ void __launch_bounds__(256, 3)
spconv_main(const short* __restrict__ featb, const short* __restrict__ wtb,
            const int* __restrict__ idx, float* __restrict__ out)
{
    __shared__ short Bs[4][WTB_K];   // 4 x 6KB single-k B buffers

    const int tid  = threadIdx.x;
    const int lane = tid & 63;
    const int wave = tid >> 6;
    const int l32  = lane & 31;
    const int hi   = lane >> 5;      // 0/1: which 8-k half this lane holds

    // XCD-contiguous swizzle (bijective for bid<776, identity tail)
    int bid = blockIdx.x;
    int sb  = (bid < 776) ? ((bid & 7) * 97 + (bid >> 3)) : bid;

    const int m0   = (sb * 4 + wave) * 32;     // 32 rows per wave
    const bool act = (m0 < NVOX);              // whole-wave validity (NVOX%32==0)
    const int rr   = act ? (m0 + l32) : 0;     // this lane's voxel row

    floatx16 acc[2];
    #pragma unroll
    for (int nt = 0; nt < 2; ++nt)
        #pragma unroll
        for (int r = 0; r < 16; ++r) acc[nt][r] = 0.f;

    short8 A[2][3];      // [k&1][ks] A-frag ring
    short8 bst[2][2];    // [k&1][half] B-stage ring (half 1 only for tid<128)
    int    rowg[4];      // [k&3] gathered row (idx<0 -> NVOX zero row)

    auto ldrow = [&](int k) {
        int t0 = idx[k * NVOX + rr];
        rowg[k & 3] = (t0 < 0) ? NVOX : t0;
    };
    auto aload = [&](int k) {
        const short* p = featb + rowg[k & 3] * FEAT_ROW + hi * 8;
        A[k & 1][0] = *(const short8*)(p);
        A[k & 1][1] = *(const short8*)(p + 16);
        A[k & 1][2] = *(const short8*)(p + 32);
    };
    auto bload = [&](int k) {
        bst[k & 1][0] = *(const short8*)(wtb + k * WTB_K + tid * 8);
        if (tid < 128)
            bst[k & 1][1] = *(const short8*)(wtb + k * WTB_K + 2048 + tid * 8);
    };
    auto compute = [&](int k) {
        #pragma unroll
        for (int ks = 0; ks < 3; ++ks) {
            short8 b0 = *(const short8*)&Bs[k & 3][(ks * 128 + lane) * 8];
            short8 b1 = *(const short8*)&Bs[k & 3][(ks * 128 + 64 + lane) * 8];
            acc[0] = __builtin_amdgcn_mfma_f32_32x32x16_bf16(
                A[k & 1][ks], b0, acc[0], 0, 0, 0);
            acc[1] = __builtin_amdgcn_mfma_f32_32x32x16_bf16(
                A[k & 1][ks], b1, acc[1], 0, 0, 0);
        }
    };

    // ---- prologue ----
    ldrow(0); ldrow(1); ldrow(2); ldrow(3);
    bload(0); bload(1);
    aload(0); aload(1);

    #pragma unroll
    for (int j = 0; j < 14; ++j) {
        const int kk = 2 * j;

        // commit staged B(kk), B(kk+1) regs to LDS buffers kk&3, (kk+1)&3
        *(short8*)&Bs[kk & 3][tid * 8] = bst[0][0];
        if (tid < 128) *(short8*)&Bs[kk & 3][2048 + tid * 8] = bst[0][1];
        if (kk + 1 < KOFF) {
            *(short8*)&Bs[(kk + 1) & 3][tid * 8] = bst[1][0];
            if (tid < 128) *(short8*)&Bs[(kk + 1) & 3][2048 + tid * 8] = bst[1][1];
        }
        __syncthreads();

        // stage next pair's B into regs; idx two pairs ahead
        if (kk + 2 < KOFF) bload(kk + 2);
        if (kk + 3 < KOFF) bload(kk + 3);
        if (kk + 4 < KOFF) ldrow(kk + 4);
        if (kk + 5 < KOFF) ldrow(kk + 5);

        compute(kk);
        if (kk + 2 < KOFF) aload(kk + 2);     // refills A[kk&1] after use
        if (kk + 1 < KOFF) {
            compute(kk + 1);
            if (kk + 3 < KOFF) aload(kk + 3);
        }
    }

    // ---- epilogue: D col = nt*32 + (lane&31), row = (r&3) + 8*(r>>2) + 4*hi ----
    if (act) {
        #pragma unroll
        for (int nt = 0; nt < 2; ++nt) {
            #pragma unroll
            for (int r = 0; r < 16; ++r) {
                int row = (r & 3) + 8 * (r >> 2) + 4 * hi;
                out[(m0 + row) * OUTC + nt * 32 + l32] = acc[nt][r];
            }
        }
    }
}

// Safety fallback (only if workspace were too small): plain fp32.
__global__ void __launch_bounds__(256)
spconv_fallback(const float* __restrict__ feat, const float* __restrict__ wk,
                const int* __restrict__ idx, float* __restrict__ out)
{
    int t = blockIdx.x * 256 + threadIdx.x;
    if (t >= NVOX * OUTC) return;
    int n = t >> 6, o = t & 63;
    float s = 0.f;
    for (int k = 0; k < KOFF; ++k) {
        int g = idx[k * NVOX + n];
        if (g >= 0) {
            const float* fr = feat + g * INC;
            const float* wr = wk + k * (INC_MAX * OUTC_MAX) + o;
            #pragma unroll 8
            for (int c = 0; c < INC; ++c) s += fr[c] * wr[c * OUTC_MAX];
        }
    }
    out[t] = s;
}

extern "C" void kernel_launch(void* const* d_in, const int* in_sizes, int n_in,
                              void* d_out, int out_size, void* d_ws, size_t ws_size,
                              hipStream_t stream) {
    const float* feat = (const float*)d_in[0];
    const float* wk   = (const float*)d_in[1];
    const int*   idx  = (const int*)d_in[2];
    float* out = (float*)d_out;

    if (ws_size >= WS_NEED) {
        short* featb = (short*)d_ws;
        short* wtb   = featb + FEATB_ELEMS;
        prep_cvt<<<FEAT_PREP_BLKS + WTB_PREP_BLKS, 256, 0, stream>>>(feat, wk, featb, wtb);
        spconv_main<<<MAIN_BLOCKS, 256, 0, stream>>>(featb, wtb, idx, out);
    } else {
        spconv_fallback<<<(NVOX * OUTC + 255) / 256, 256, 0, stream>>>(feat, wk, idx, out);
    }
}